// Round 12
// baseline (188.798 us; speedup 1.0000x reference)
//
#include <hip/hip_runtime.h>
#include <math.h>

#define NOBS 9

typedef float f2 __attribute__((ext_vector_type(2)));

__device__ __forceinline__ float silu_f(float x) { return x / (1.f + expf(-x)); }
__device__ __forceinline__ f2 splat2(float x) { return (f2){x, x}; }
__device__ __forceinline__ f2 fma2(f2 a, f2 b, f2 c) { return __builtin_elementwise_fma(a, b, c); }

// ---------------- lane-exchange primitives (R8-verified) ----------------
template<int CTRL>
__device__ __forceinline__ float dpp_perm(float x) {
  return __int_as_float(__builtin_amdgcn_update_dpp(0, __float_as_int(x), CTRL, 0xF, 0xF, true));
}
template<int PAT>
__device__ __forceinline__ float ds_swz(float x) {
  return __int_as_float(__builtin_amdgcn_ds_swizzle(__float_as_int(x), PAT));
}
__device__ __forceinline__ float x4f(float x) { return ds_swz<0x101F>(x); }   // xor4

__device__ __forceinline__ float wave_sum(float x) {
  x += dpp_perm<0xB1>(x);
  x += dpp_perm<0x4E>(x);
  x += x4f(x);
  x += dpp_perm<0x128>(x);
  x += ds_swz<0x401F>(x);
  x += __shfl_xor(x, 32, 64);
  return x;
}

// ---------------- circuit gates (16 regs/lane, 1 wave/row; R8-verified) ----------------
template<int M>
__device__ __forceinline__ void ry_reg(float v[16], float c, float s) {
#pragma unroll
  for (int r = 0; r < 16; ++r) {
    if ((r & M) == 0) {
      float p0 = v[r], p1 = v[r | M];
      v[r]     = c * p0 - s * p1;
      v[r | M] = s * p0 + c * p1;
    }
  }
}

__device__ __forceinline__ void apply_rys(float v[16], int lane,
                                          const float* __restrict__ cc,
                                          const float* __restrict__ ss) {
  ry_reg<8>(v, cc[0], ss[0]);
  ry_reg<4>(v, cc[1], ss[1]);
  ry_reg<2>(v, cc[2], ss[2]);
  ry_reg<1>(v, cc[3], ss[3]);
  { float c = cc[4], s = ss[4], sp = (lane & 32) ? s : -s;
#pragma unroll
    for (int r = 0; r < 16; ++r) { float p = __shfl_xor(v[r], 32, 64); v[r] = fmaf(c, v[r], sp * p); } }
  { float c = cc[5], s = ss[5], sp = (lane & 16) ? s : -s;
#pragma unroll
    for (int r = 0; r < 16; ++r) { float p = __shfl_xor(v[r], 16, 64); v[r] = fmaf(c, v[r], sp * p); } }
  { float c = cc[6], s = ss[6], sp = (lane & 8) ? s : -s;
#pragma unroll
    for (int r = 0; r < 16; ++r) { float p = dpp_perm<0x128>(v[r]); v[r] = fmaf(c, v[r], sp * p); } }
  { float c = cc[7], s = ss[7], sp = (lane & 4) ? s : -s;
#pragma unroll
    for (int r = 0; r < 16; ++r) { float p = x4f(v[r]); v[r] = fmaf(c, v[r], sp * p); } }
  { float c = cc[8], s = ss[8], sp = (lane & 2) ? s : -s;
#pragma unroll
    for (int r = 0; r < 16; ++r) { float p = dpp_perm<0x4E>(v[r]); v[r] = fmaf(c, v[r], sp * p); } }
  { float c = cc[9], s = ss[9], sp = (lane & 1) ? s : -s;
#pragma unroll
    for (int r = 0; r < 16; ++r) { float p = dpp_perm<0xB1>(v[r]); v[r] = fmaf(c, v[r], sp * p); } }
}

__device__ __forceinline__ void cnot_ladder(float v[16], int lane) {
  float t;
  t=v[8];  v[8]=v[12];  v[12]=t;
  t=v[9];  v[9]=v[13];  v[13]=t;
  t=v[10]; v[10]=v[14]; v[14]=t;
  t=v[11]; v[11]=v[15]; v[15]=t;
  t=v[2];  v[2]=v[3];   v[3]=t;
  t=v[6];  v[6]=v[7];   v[7]=t;
  t=v[10]; v[10]=v[11]; v[11]=t;
  t=v[14]; v[14]=v[15]; v[15]=t;
  int se = lane ^ ((lane & 42) >> 1);
#pragma unroll
  for (int r = 0; r < 16; ++r) v[r] = __shfl(v[r], se, 64);
  t=v[4];  v[4]=v[6];   v[6]=t;
  t=v[5];  v[5]=v[7];   v[7]=t;
  t=v[12]; v[12]=v[14]; v[14]=t;
  t=v[13]; v[13]=v[15]; v[15]=t;
  int so  = lane ^ ((lane & 20) >> 1);
  int so1 = so ^ 32;
#pragma unroll
  for (int r = 0; r < 16; ++r) v[r] = __shfl(v[r], (r & 1) ? so1 : so, 64);
}

// ---------------- kernel 0: var-layer cos/sin ----------------
__global__ __launch_bounds__(64) void varcs_kernel(const float* __restrict__ varp,
                                                   float* __restrict__ varc,
                                                   float* __restrict__ vars) {
  int tid = threadIdx.x;
  if (tid < 60) {
    float s, c;
    sincosf(0.5f * varp[tid], &s, &c);
    varc[tid] = c;
    vars[tid] = s;
  }
}

// ---------------- kernel 1: enc (phases 1-3), 4 rows / 256 threads ----------------
__global__ __launch_bounds__(256) void enc_kernel(
    const float* __restrict__ z, const float* __restrict__ t,
    const float* __restrict__ W1, const float* __restrict__ b1,
    const float* __restrict__ W2, const float* __restrict__ b2,
    float* __restrict__ csg, float* __restrict__ sng) {
  __shared__ __align__(16) float4 xs4[256];
  __shared__ float hs[4][256];
  int tid = threadIdx.x;
  int b0 = blockIdx.x * 4;

  // phase 1: x = [z, cos(t f), sin(t f)] packed by row quadruple
  if (tid < 128) {
    xs4[tid] = (float4){z[(b0 + 0) * 128 + tid], z[(b0 + 1) * 128 + tid],
                        z[(b0 + 2) * 128 + tid], z[(b0 + 3) * 128 + tid]};
  } else {
    int i = tid - 128, j = i & 63;
    float freq = expf(-9.2103403719761836f * (float)j * (1.f / 64.f));
    float a0 = t[b0] * freq, a1 = t[b0 + 1] * freq, a2 = t[b0 + 2] * freq, a3 = t[b0 + 3] * freq;
    xs4[tid] = (i < 64) ? (float4){cosf(a0), cosf(a1), cosf(a2), cosf(a3)}
                        : (float4){sinf(a0), sinf(a1), sinf(a2), sinf(a3)};
  }
  __syncthreads();

  // phase 2: h = silu(x@W1 + b1)
  {
    f2 a01 = splat2(b1[tid]), a23 = a01;
#pragma unroll 8
    for (int k = 0; k < 256; ++k) {
      float wv = W1[k * 256 + tid];
      float4 x = xs4[k];
      a01 = fma2((f2){x.x, x.y}, splat2(wv), a01);
      a23 = fma2((f2){x.z, x.w}, splat2(wv), a23);
    }
    hs[0][tid] = silu_f(a01.x);
    hs[1][tid] = silu_f(a01.y);
    hs[2][tid] = silu_f(a23.x);
    hs[3][tid] = silu_f(a23.y);
  }
  __syncthreads();

  // phase 3: ang = h@W2 + b2 -> cos/sin(ang/2)
  if (tid < 160) {
    int r = tid / 40, c = tid - r * 40;
    float acc = b2[c];
#pragma unroll 8
    for (int k = 0; k < 256; ++k)
      acc = fmaf(hs[r][k], W2[k * 40 + c], acc);
    float s, cv;
    sincosf(0.5f * acc, &s, &cv);
    csg[(b0 + r) * 40 + c] = cv;
    sng[(b0 + r) * 40 + c] = s;
  }
}

// ---------------- kernel 2: circuit, 1 row / 64-thread block ----------------
__global__ __launch_bounds__(64) void circuit_kernel(
    const float* __restrict__ csg, const float* __restrict__ sng,
    const float* __restrict__ varc, const float* __restrict__ vars,
    const float* __restrict__ A_p, const float* __restrict__ D_p,
    float* __restrict__ obs) {
  __shared__ float sw[1024];
  int lane = threadIdx.x;
  int b = blockIdx.x;
  const float* cc = csg + b * 40;
  const float* ss = sng + b * 40;

  // layer 0 on |0..0>: product state
  float base = 1.f;
  base *= (lane & 32) ? ss[4] : cc[4];
  base *= (lane & 16) ? ss[5] : cc[5];
  base *= (lane & 8)  ? ss[6] : cc[6];
  base *= (lane & 4)  ? ss[7] : cc[7];
  base *= (lane & 2)  ? ss[8] : cc[8];
  base *= (lane & 1)  ? ss[9] : cc[9];
  float v[16];
#pragma unroll
  for (int r = 0; r < 16; ++r) {
    float p = base;
    p *= (r & 8) ? ss[0] : cc[0];
    p *= (r & 4) ? ss[1] : cc[1];
    p *= (r & 2) ? ss[2] : cc[2];
    p *= (r & 1) ? ss[3] : cc[3];
    v[r] = p;
  }
  cnot_ladder(v, lane);
#pragma unroll 1
  for (int layer = 1; layer < 4; ++layer) {
    apply_rys(v, lane, cc + layer * 10, ss + layer * 10);
    if (layer < 3) cnot_ladder(v, lane);
  }
#pragma unroll 1
  for (int ly = 0; ly < 6; ++ly) {
    apply_rys(v, lane, varc + ly * 10, vars + ly * 10);
    cnot_ladder(v, lane);
  }

#pragma unroll
  for (int r = 0; r < 16; ++r) sw[r * 64 + lane] = v[r];

#pragma unroll 1
  for (int s = 0; s < NOBS; ++s) {
    const int r8 = 8 - s;
    const int stride = 1 << r8;
    float h10 = A_p[s*6+0], h20 = A_p[s*6+1], h21 = A_p[s*6+2];
    float h30 = A_p[s*6+3], h31 = A_p[s*6+4], h32 = A_p[s*6+5];
    float d0 = 2.f * D_p[s*4+1], d1 = 2.f * D_p[s*4+2], d2 = 2.f * D_p[s*4+3];
    float acc = 0.f;
#pragma unroll
    for (int k = 0; k < 4; ++k) {
      int p = lane + 64 * k;
      int a  = p >> r8;
      int rr = p & (stride - 1);
      int bse = (a << (r8 + 2)) + rr;
      float x0 = sw[bse];
      float x1 = sw[bse + stride];
      float x2 = sw[bse + 2 * stride];
      float x3 = sw[bse + 3 * stride];
      acc += d0 * x0 * x0 + d1 * x1 * x1 + d2 * x2 * x2
           + 2.f * (h10 * x1 * x0 + h20 * x2 * x0 + h21 * x2 * x1
                  + h30 * x3 * x0 + h31 * x3 * x1 + h32 * x3 * x2);
    }
    acc = wave_sum(acc);
    if (lane == 0) obs[b * NOBS + s] = acc;
  }
}

// ---------------- kernel 3: head (phase 5), 4 rows / 256 threads ----------------
__global__ __launch_bounds__(256) void head_kernel(
    const float* __restrict__ obs, const float* __restrict__ W3,
    const float* __restrict__ b3, const float* __restrict__ W4,
    const float* __restrict__ b4, float* __restrict__ out) {
  __shared__ float os[4][NOBS];
  __shared__ __align__(16) float4 hp4[256];
  int tid = threadIdx.x;
  int b0 = blockIdx.x * 4;

  if (tid < 4 * NOBS) os[tid / NOBS][tid % NOBS] = obs[b0 * NOBS + tid];
  __syncthreads();

  // 5a: hh = silu(obs@W3 + b3)
  {
    f2 q01 = splat2(b3[tid]), q23 = q01;
#pragma unroll
    for (int s = 0; s < NOBS; ++s) {
      float wv = W3[s * 256 + tid];
      q01 = fma2((f2){os[0][s], os[1][s]}, splat2(wv), q01);
      q23 = fma2((f2){os[2][s], os[3][s]}, splat2(wv), q23);
    }
    hp4[tid] = (float4){silu_f(q01.x), silu_f(q01.y), silu_f(q23.x), silu_f(q23.y)};
  }
  __syncthreads();

  // 5b: out = hh@W4 + b4
  {
    int c = tid & 127, rg = tid >> 7;   // rg=0 -> rows 0,1 ; rg=1 -> rows 2,3
    f2 acc = splat2(b4[c]);
#pragma unroll 8
    for (int k = 0; k < 256; ++k) {
      float wv = W4[k * 128 + c];
      float4 h = hp4[k];
      f2 hp = (rg == 0) ? (f2){h.x, h.y} : (f2){h.z, h.w};
      acc = fma2(hp, splat2(wv), acc);
    }
    out[(b0 + 2 * rg) * 128 + c]     = acc.x;
    out[(b0 + 2 * rg + 1) * 128 + c] = acc.y;
  }
}

// ---------------- launcher ----------------
// DIAGNOSTIC ROUND: circuit runs 3x into distinct obs buffers (identical outputs,
// real global writes -> no DCE). head consumes the 3rd. dur delta vs R11 = 2x circuit cost.

extern "C" void kernel_launch(void* const* d_in, const int* in_sizes, int n_in,
                              void* d_out, int out_size, void* d_ws, size_t ws_size,
                              hipStream_t stream) {
  const float* z_t  = (const float*)d_in[0];
  const float* t    = (const float*)d_in[1];
  const float* W1   = (const float*)d_in[2];
  const float* b1   = (const float*)d_in[3];
  const float* W2   = (const float*)d_in[4];
  const float* b2   = (const float*)d_in[5];
  const float* varp = (const float*)d_in[6];
  const float* A_p  = (const float*)d_in[7];
  // d_in[8] = B_p: imaginary part of H -> contributes 0 for real psi
  const float* D_p  = (const float*)d_in[9];
  const float* W3   = (const float*)d_in[10];
  const float* b3   = (const float*)d_in[11];
  const float* W4   = (const float*)d_in[12];
  const float* b4   = (const float*)d_in[13];
  float* out = (float*)d_out;

  int B = in_sizes[1];  // t has one element per batch row

  float* csg  = (float*)d_ws;                 // B*40
  float* sng  = csg + (size_t)B * 40;         // B*40
  float* obs0 = sng + (size_t)B * 40;         // B*9
  float* obs1 = obs0 + (size_t)B * 9;         // B*9
  float* obs2 = obs1 + (size_t)B * 9;         // B*9
  float* varc = obs2 + (size_t)B * 9;         // 64
  float* vars = varc + 64;                    // 64

  varcs_kernel<<<1, 64, 0, stream>>>(varp, varc, vars);
  enc_kernel<<<B / 4, 256, 0, stream>>>(z_t, t, W1, b1, W2, b2, csg, sng);
  circuit_kernel<<<B, 64, 0, stream>>>(csg, sng, varc, vars, A_p, D_p, obs0);
  circuit_kernel<<<B, 64, 0, stream>>>(csg, sng, varc, vars, A_p, D_p, obs1);
  circuit_kernel<<<B, 64, 0, stream>>>(csg, sng, varc, vars, A_p, D_p, obs2);
  head_kernel<<<B / 4, 256, 0, stream>>>(obs2, W3, b3, W4, b4, out);
}

// Round 13
// 130.068 us; speedup vs baseline: 1.4515x; 1.4515x over previous
//
#include <hip/hip_runtime.h>
#include <math.h>

#define NOBS 9

typedef float f2 __attribute__((ext_vector_type(2)));

__device__ __forceinline__ float silu_f(float x) { return x / (1.f + expf(-x)); }
__device__ __forceinline__ f2 splat2(float x) { return (f2){x, x}; }
__device__ __forceinline__ f2 fma2(f2 a, f2 b, f2 c) { return __builtin_elementwise_fma(a, b, c); }

// ---------------- lane-exchange primitives (R8-verified) ----------------
template<int CTRL>
__device__ __forceinline__ float dpp_perm(float x) {
  return __int_as_float(__builtin_amdgcn_update_dpp(0, __float_as_int(x), CTRL, 0xF, 0xF, true));
}
template<int PAT>
__device__ __forceinline__ float ds_swz(float x) {
  return __int_as_float(__builtin_amdgcn_ds_swizzle(__float_as_int(x), PAT));
}
__device__ __forceinline__ float x4f(float x) { return ds_swz<0x101F>(x); }   // xor4

__device__ __forceinline__ float wave_sum(float x) {
  x += dpp_perm<0xB1>(x);
  x += dpp_perm<0x4E>(x);
  x += x4f(x);
  x += dpp_perm<0x128>(x);
  x += ds_swz<0x401F>(x);
  x += __shfl_xor(x, 32, 64);
  return x;
}

// ---------------- circuit gates (16 regs/lane, 1 wave/row; R8-verified) ----------------
template<int M>
__device__ __forceinline__ void ry_reg(float v[16], float c, float s) {
#pragma unroll
  for (int r = 0; r < 16; ++r) {
    if ((r & M) == 0) {
      float p0 = v[r], p1 = v[r | M];
      v[r]     = c * p0 - s * p1;
      v[r | M] = s * p0 + c * p1;
    }
  }
}

__device__ __forceinline__ void apply_rys(float v[16], int lane,
                                          const float* __restrict__ cc,
                                          const float* __restrict__ ss) {
  ry_reg<8>(v, cc[0], ss[0]);
  ry_reg<4>(v, cc[1], ss[1]);
  ry_reg<2>(v, cc[2], ss[2]);
  ry_reg<1>(v, cc[3], ss[3]);
  { float c = cc[4], s = ss[4], sp = (lane & 32) ? s : -s;
#pragma unroll
    for (int r = 0; r < 16; ++r) { float p = __shfl_xor(v[r], 32, 64); v[r] = fmaf(c, v[r], sp * p); } }
  { float c = cc[5], s = ss[5], sp = (lane & 16) ? s : -s;
#pragma unroll
    for (int r = 0; r < 16; ++r) { float p = __shfl_xor(v[r], 16, 64); v[r] = fmaf(c, v[r], sp * p); } }
  { float c = cc[6], s = ss[6], sp = (lane & 8) ? s : -s;
#pragma unroll
    for (int r = 0; r < 16; ++r) { float p = dpp_perm<0x128>(v[r]); v[r] = fmaf(c, v[r], sp * p); } }
  { float c = cc[7], s = ss[7], sp = (lane & 4) ? s : -s;
#pragma unroll
    for (int r = 0; r < 16; ++r) { float p = x4f(v[r]); v[r] = fmaf(c, v[r], sp * p); } }
  { float c = cc[8], s = ss[8], sp = (lane & 2) ? s : -s;
#pragma unroll
    for (int r = 0; r < 16; ++r) { float p = dpp_perm<0x4E>(v[r]); v[r] = fmaf(c, v[r], sp * p); } }
  { float c = cc[9], s = ss[9], sp = (lane & 1) ? s : -s;
#pragma unroll
    for (int r = 0; r < 16; ++r) { float p = dpp_perm<0xB1>(v[r]); v[r] = fmaf(c, v[r], sp * p); } }
}

__device__ __forceinline__ void cnot_ladder(float v[16], int lane) {
  float t;
  t=v[8];  v[8]=v[12];  v[12]=t;
  t=v[9];  v[9]=v[13];  v[13]=t;
  t=v[10]; v[10]=v[14]; v[14]=t;
  t=v[11]; v[11]=v[15]; v[15]=t;
  t=v[2];  v[2]=v[3];   v[3]=t;
  t=v[6];  v[6]=v[7];   v[7]=t;
  t=v[10]; v[10]=v[11]; v[11]=t;
  t=v[14]; v[14]=v[15]; v[15]=t;
  int se = lane ^ ((lane & 42) >> 1);
#pragma unroll
  for (int r = 0; r < 16; ++r) v[r] = __shfl(v[r], se, 64);
  t=v[4];  v[4]=v[6];   v[6]=t;
  t=v[5];  v[5]=v[7];   v[7]=t;
  t=v[12]; v[12]=v[14]; v[14]=t;
  t=v[13]; v[13]=v[15]; v[15]=t;
  int so  = lane ^ ((lane & 20) >> 1);
  int so1 = so ^ 32;
#pragma unroll
  for (int r = 0; r < 16; ++r) v[r] = __shfl(v[r], (r & 1) ? so1 : so, 64);
}

// ---------------- fused kernel: 4 rows / 256 threads; k-staggered GEMV loops ----------------

__global__ __launch_bounds__(256) void fused_kernel(
    const float* __restrict__ z, const float* __restrict__ t,
    const float* __restrict__ W1, const float* __restrict__ b1,
    const float* __restrict__ W2, const float* __restrict__ b2,
    const float* __restrict__ varp,
    const float* __restrict__ A_p, const float* __restrict__ D_p,
    const float* __restrict__ W3, const float* __restrict__ b3,
    const float* __restrict__ W4, const float* __restrict__ b4,
    float* __restrict__ out) {
  __shared__ __align__(16) float4 xs4[256];
  __shared__ float hs[4][256];
  __shared__ float dump[4][1024];
  __shared__ float cs[4][40], sn[4][40];
  __shared__ float vcs[64], vsn[64];
  __shared__ float os[4][NOBS];
  __shared__ __align__(16) float4 hp4[256];

  int tid = threadIdx.x;
  int b0 = blockIdx.x * 4;
  int wave = tid >> 6;
  int lane = tid & 63;
  // per-wave k-phase stagger: decorrelates the chip-wide weight address stream
  // (breaks the same-L2-line convoy; 53 is odd -> full period mod 256)
  int koff = (((blockIdx.x << 2) | wave) * 53) & 255;

  if (tid < 60) {
    float s, c;
    sincosf(0.5f * varp[tid], &s, &c);
    vcs[tid] = c; vsn[tid] = s;
  }

  // ---- phase 1: x = [z, cos(t f), sin(t f)] packed by row quadruple ----
  if (tid < 128) {
    xs4[tid] = (float4){z[(b0 + 0) * 128 + tid], z[(b0 + 1) * 128 + tid],
                        z[(b0 + 2) * 128 + tid], z[(b0 + 3) * 128 + tid]};
  } else {
    int i = tid - 128, j = i & 63;
    float freq = expf(-9.2103403719761836f * (float)j * (1.f / 64.f));
    float a0 = t[b0] * freq, a1 = t[b0 + 1] * freq, a2 = t[b0 + 2] * freq, a3 = t[b0 + 3] * freq;
    xs4[tid] = (i < 64) ? (float4){cosf(a0), cosf(a1), cosf(a2), cosf(a3)}
                        : (float4){sinf(a0), sinf(a1), sinf(a2), sinf(a3)};
  }
  __syncthreads();

  // ---- phase 2: h = silu(x@W1 + b1), k staggered per wave ----
  {
    f2 a01 = splat2(b1[tid]), a23 = a01;
#pragma unroll 8
    for (int j = 0; j < 256; ++j) {
      int k = (koff + j) & 255;
      float wv = W1[k * 256 + tid];
      float4 x = xs4[k];
      a01 = fma2((f2){x.x, x.y}, splat2(wv), a01);
      a23 = fma2((f2){x.z, x.w}, splat2(wv), a23);
    }
    hs[0][tid] = silu_f(a01.x);
    hs[1][tid] = silu_f(a01.y);
    hs[2][tid] = silu_f(a23.x);
    hs[3][tid] = silu_f(a23.y);
  }
  __syncthreads();

  // ---- phase 3: ang = h@W2 + b2 -> cos/sin(ang/2), k staggered ----
  if (tid < 160) {
    int r = tid / 40, c = tid - r * 40;
    float acc = b2[c];
#pragma unroll 8
    for (int j = 0; j < 256; ++j) {
      int k = (koff + j) & 255;
      acc = fmaf(hs[r][k], W2[k * 40 + c], acc);
    }
    float s, cv;
    sincosf(0.5f * acc, &s, &cv);
    cs[r][c] = cv; sn[r][c] = s;
  }
  __syncthreads();

  // ---- phase 4: circuit (wave = row, 16 amps/lane) ----
  {
    const float* cc = cs[wave];
    const float* ss = sn[wave];

    float base = 1.f;
    base *= (lane & 32) ? ss[4] : cc[4];
    base *= (lane & 16) ? ss[5] : cc[5];
    base *= (lane & 8)  ? ss[6] : cc[6];
    base *= (lane & 4)  ? ss[7] : cc[7];
    base *= (lane & 2)  ? ss[8] : cc[8];
    base *= (lane & 1)  ? ss[9] : cc[9];
    float v[16];
#pragma unroll
    for (int r = 0; r < 16; ++r) {
      float p = base;
      p *= (r & 8) ? ss[0] : cc[0];
      p *= (r & 4) ? ss[1] : cc[1];
      p *= (r & 2) ? ss[2] : cc[2];
      p *= (r & 1) ? ss[3] : cc[3];
      v[r] = p;
    }
    cnot_ladder(v, lane);
#pragma unroll 1
    for (int layer = 1; layer < 4; ++layer) {
      apply_rys(v, lane, cc + layer * 10, ss + layer * 10);
      if (layer < 3) cnot_ladder(v, lane);
    }
#pragma unroll 1
    for (int ly = 0; ly < 6; ++ly) {
      apply_rys(v, lane, vcs + ly * 10, vsn + ly * 10);
      cnot_ladder(v, lane);
    }

    float* sw = dump[wave];
#pragma unroll
    for (int r = 0; r < 16; ++r) sw[r * 64 + lane] = v[r];

#pragma unroll 1
    for (int s = 0; s < NOBS; ++s) {
      const int r8 = 8 - s;
      const int stride = 1 << r8;
      float h10 = A_p[s*6+0], h20 = A_p[s*6+1], h21 = A_p[s*6+2];
      float h30 = A_p[s*6+3], h31 = A_p[s*6+4], h32 = A_p[s*6+5];
      float d0 = 2.f * D_p[s*4+1], d1 = 2.f * D_p[s*4+2], d2 = 2.f * D_p[s*4+3];
      float acc = 0.f;
#pragma unroll
      for (int k = 0; k < 4; ++k) {
        int p = lane + 64 * k;
        int a  = p >> r8;
        int rr = p & (stride - 1);
        int bse = (a << (r8 + 2)) + rr;
        float x0 = sw[bse];
        float x1 = sw[bse + stride];
        float x2 = sw[bse + 2 * stride];
        float x3 = sw[bse + 3 * stride];
        acc += d0 * x0 * x0 + d1 * x1 * x1 + d2 * x2 * x2
             + 2.f * (h10 * x1 * x0 + h20 * x2 * x0 + h21 * x2 * x1
                    + h30 * x3 * x0 + h31 * x3 * x1 + h32 * x3 * x2);
      }
      acc = wave_sum(acc);
      if (lane == 0) os[wave][s] = acc;
    }
  }
  __syncthreads();

  // ---- phase 5a: hh = silu(obs@W3 + b3) ----
  {
    f2 q01 = splat2(b3[tid]), q23 = q01;
#pragma unroll
    for (int s = 0; s < NOBS; ++s) {
      float wv = W3[s * 256 + tid];
      q01 = fma2((f2){os[0][s], os[1][s]}, splat2(wv), q01);
      q23 = fma2((f2){os[2][s], os[3][s]}, splat2(wv), q23);
    }
    hp4[tid] = (float4){silu_f(q01.x), silu_f(q01.y), silu_f(q23.x), silu_f(q23.y)};
  }
  __syncthreads();

  // ---- phase 5b: out = hh@W4 + b4, k staggered ----
  {
    int c = tid & 127, rg = tid >> 7;   // rg=0 -> rows 0,1 ; rg=1 -> rows 2,3
    f2 acc = splat2(b4[c]);
#pragma unroll 8
    for (int j = 0; j < 256; ++j) {
      int k = (koff + j) & 255;
      float wv = W4[k * 128 + c];
      float4 h = hp4[k];
      f2 hp = rg ? (f2){h.z, h.w} : (f2){h.x, h.y};
      acc = fma2(hp, splat2(wv), acc);
    }
    out[(b0 + 2 * rg) * 128 + c]     = acc.x;
    out[(b0 + 2 * rg + 1) * 128 + c] = acc.y;
  }
}

// ---------------- launcher ----------------

extern "C" void kernel_launch(void* const* d_in, const int* in_sizes, int n_in,
                              void* d_out, int out_size, void* d_ws, size_t ws_size,
                              hipStream_t stream) {
  const float* z_t  = (const float*)d_in[0];
  const float* t    = (const float*)d_in[1];
  const float* W1   = (const float*)d_in[2];
  const float* b1   = (const float*)d_in[3];
  const float* W2   = (const float*)d_in[4];
  const float* b2   = (const float*)d_in[5];
  const float* varp = (const float*)d_in[6];
  const float* A_p  = (const float*)d_in[7];
  // d_in[8] = B_p: imaginary part of H -> contributes 0 for real psi
  const float* D_p  = (const float*)d_in[9];
  const float* W3   = (const float*)d_in[10];
  const float* b3   = (const float*)d_in[11];
  const float* W4   = (const float*)d_in[12];
  const float* b4   = (const float*)d_in[13];
  float* out = (float*)d_out;

  int B = in_sizes[1];  // t has one element per batch row

  fused_kernel<<<B / 4, 256, 0, stream>>>(z_t, t, W1, b1, W2, b2, varp,
                                          A_p, D_p, W3, b3, W4, b4, out);
}